// Round 1
// 498.085 us; speedup vs baseline: 1.0039x; 1.0039x over previous
//
#include <hip/hip_runtime.h>

// Bilinear grid sample, B=8 H=512 W=512 C=32, fp32.
// Mapping: 8 threads per output pixel; thread handles float4 of channels.
//  - gathered img pixel = one aligned 128B line, read by 8 consecutive lanes
//    as coalesced float4s -> full line utilization.
//  - stores: wave writes 1KiB contiguous, NON-TEMPORAL so the 268MB write
//    stream does not evict img (256MB, exactly L3-sized) from Infinity Cache.
//    Theory: FETCH_SIZE 487MB -> ~290MB (img L3-resident; floor = 256+17MB).

typedef float f4_t __attribute__((ext_vector_type(4)));

__global__ __launch_bounds__(256) void Interpolate_86775519248465_kernel(
    const float* __restrict__ img,
    const float* __restrict__ grid,
    float* __restrict__ out)
{
    constexpr int W = 512;
    constexpr int C = 32;
    constexpr float MAXX = 511.0f;   // W-1
    constexpr float MAXY = 511.0f;   // H-1

    const unsigned gid = blockIdx.x * 256u + threadIdx.x;
    const unsigned pix = gid >> 3;           // pixel index in [0, B*H*W)
    const unsigned c   = (gid & 7u) << 2;    // channel start (float4)

    // grid lookup: [B,H,W,2] flat -> float2 at pix
    const float2 g = *reinterpret_cast<const float2*>(grid + (size_t)pix * 2u);

    const float x = 0.5f * ((g.x + 1.0f) * MAXX);
    const float y = 0.5f * ((g.y + 1.0f) * MAXY);

    const int x0 = (int)floorf(x);
    const int y0 = (int)floorf(y);
    const int x1 = x0 + 1;
    const int y1 = y0 + 1;

    const int x0c = min(max(x0, 0), 511);
    const int x1c = min(max(x1, 0), 511);
    const int y0c = min(max(y0, 0), 511);
    const int y1c = min(max(y1, 0), 511);

    // weights from CLIPPED coords (matches reference exactly)
    const float x0f = (float)x0c, x1f = (float)x1c;
    const float y0f = (float)y0c, y1f = (float)y1c;
    const float wa = (x1f - x) * (y1f - y);
    const float wb = (x1f - x) * (y - y0f);
    const float wc = (x - x0f) * (y1f - y);
    const float wd = (x - x0f) * (y - y0f);

    // img base: b*H*W*C ; H*W = 2^18
    const unsigned b = pix >> 18;
    const size_t base = ((size_t)b << 18) * (size_t)C;

    const size_t ia = base + ((size_t)((unsigned)y0c * W + (unsigned)x0c) * C) + c;
    const size_t ib = base + ((size_t)((unsigned)y1c * W + (unsigned)x0c) * C) + c;
    const size_t ic = base + ((size_t)((unsigned)y0c * W + (unsigned)x1c) * C) + c;
    const size_t id = base + ((size_t)((unsigned)y1c * W + (unsigned)x1c) * C) + c;

    const float4 Ia = *reinterpret_cast<const float4*>(img + ia);
    const float4 Ib = *reinterpret_cast<const float4*>(img + ib);
    const float4 Ic = *reinterpret_cast<const float4*>(img + ic);
    const float4 Id = *reinterpret_cast<const float4*>(img + id);

    f4_t o;
    o.x = wa * Ia.x + wb * Ib.x + wc * Ic.x + wd * Id.x;
    o.y = wa * Ia.y + wb * Ib.y + wc * Ic.y + wd * Id.y;
    o.z = wa * Ia.z + wb * Ib.z + wc * Ic.z + wd * Id.z;
    o.w = wa * Ia.w + wb * Ib.w + wc * Ic.w + wd * Id.w;

    // Non-temporal store: out is write-once, never re-read. Keeps L3 for img.
    __builtin_nontemporal_store(o, reinterpret_cast<f4_t*>(out + (size_t)pix * C + c));
}

extern "C" void kernel_launch(void* const* d_in, const int* in_sizes, int n_in,
                              void* d_out, int out_size, void* d_ws, size_t ws_size,
                              hipStream_t stream) {
    const float* img  = (const float*)d_in[0];
    const float* grid = (const float*)d_in[1];
    float* out = (float*)d_out;

    // total threads = B*H*W*C/4 = 8*512*512*8 = 16,777,216
    const unsigned total = 8u * 512u * 512u * 8u;
    const unsigned block = 256u;
    const unsigned nblk = total / block;  // 65536
    Interpolate_86775519248465_kernel<<<nblk, block, 0, stream>>>(img, grid, out);
}